// Round 2
// baseline (14399.992 us; speedup 1.0000x reference)
//
#include <hip/hip_runtime.h>

typedef __attribute__((ext_vector_type(4))) float f32x4;

#define NSTEP 63
#define DZ 256
#define DX 64
#define DH 1024
#define RPW 8          // batch rows per workgroup
#define NT 512

__device__ __forceinline__ float tanh_fast(float x){
  float e = __expf(2.0f * x);
  return 1.0f - 2.0f / (e + 1.0f);
}

// ---------------------------------------------------------------------------
// fp32 VALU NeuralODE: 128 WGs x 512 threads, WG owns 8 batch rows, loops all
// 63 RK4 steps locally (rows independent -> zero grid syncs). No d_ws, no
// MFMA: this round isolates correctness from workspace-size and MFMA-layout
// hypotheses, and its absmax calibrates the dynamics' error amplification.
//   GEMM1 (h=z@W1+x@Wx+..): thread t owns h-cols {t, t+512}, all 8 rows.
//   GEMM2 (k=h@W2):         thread t owns k-col t&255, rows (t>>8)*4..+3.
// z state + RK4 accumulators in registers; z/h/x tiles in padded LDS
// (stride mod 32 banks = +4 -> row-parallel reads conflict-free; reads are
// wave-uniform broadcasts anyway). Weight loads are lane-consecutive ->
// coalesced; full weight set (2.25 MB fp32) is L2-resident per XCD.
// ---------------------------------------------------------------------------
__global__ __launch_bounds__(NT) void node_f32(
    const float* __restrict__ z0, const float* __restrict__ tt,
    const float* __restrict__ x,
    const float* __restrict__ W1, const float* __restrict__ Wx,
    const float* __restrict__ wt, const float* __restrict__ b1,
    const float* __restrict__ W2, const float* __restrict__ b2,
    float* __restrict__ out){

  const int wg = blockIdx.x;
  const int t  = threadIdx.x;
  const int c0 = t, c1 = t + NT;        // GEMM1 columns (0..1023)
  const int c2 = t & 255;               // GEMM2 column
  const int r0 = (t >> 8) * 4;          // GEMM2 row base (0 or 4)

  __shared__ __align__(16) float zsh[8][260];    // 260*4=1040B rows: 16B-aligned, bank+4
  __shared__ __align__(16) float hsh[8][1028];   // 1028*4=4112B rows
  __shared__ __align__(16) float xsh[8][68];     // 68*4=272B rows

  const float b1c0 = b1[c0], b1c1 = b1[c1];
  const float wtc0 = wt[c0], wtc1 = wt[c1];
  const float b2c  = b2[c2];

  float zb[4], za[4];
  #pragma unroll
  for (int i = 0; i < 4; ++i){
    zb[i] = z0[(wg * RPW + r0 + i) * DZ + c2];
    za[i] = 0.f;
    zsh[r0 + i][c2] = zb[i];
  }

  float cx0[8], cx1[8];

  for (int step = 0; step < NSTEP; ++step){
    const float t0 = tt[step], t1 = tt[step + 1];
    const float hs = t1 - t0;

    // stage x[step] rows for this WG (512 threads x 1 elem, coalesced)
    {
      int xr = t >> 6, xc = t & 63;
      xsh[xr][xc] = x[((size_t)step * 1024 + wg * RPW + xr) * DX + xc];
    }
    __syncthreads();   // xsh ready; zsh from prev stage ready

    // x-GEMM: cx = x_blk @ Wx  (held in regs as GEMM1 C-init, reused 4 stages)
    #pragma unroll
    for (int r = 0; r < 8; ++r){ cx0[r] = 0.f; cx1[r] = 0.f; }
    for (int k0 = 0; k0 < DX; k0 += 4){
      f32x4 xr4[8];
      #pragma unroll
      for (int r = 0; r < 8; ++r) xr4[r] = *(const f32x4*)&xsh[r][k0];
      float w0[4], w1[4];
      #pragma unroll
      for (int j = 0; j < 4; ++j){
        w0[j] = Wx[(k0 + j) * DH + c0];
        w1[j] = Wx[(k0 + j) * DH + c1];
      }
      #pragma unroll
      for (int j = 0; j < 4; ++j){
        #pragma unroll
        for (int r = 0; r < 8; ++r){
          cx0[r] = fmaf(xr4[r][j], w0[j], cx0[r]);
          cx1[r] = fmaf(xr4[r][j], w1[j], cx1[r]);
        }
      }
    }

    #pragma unroll 1
    for (int s = 0; s < 4; ++s){
      const float ts = (s == 0) ? t0 : ((s == 3) ? t1 : t0 + 0.5f * hs);

      // ---- GEMM1: a = z@W1 + cx ----
      float a0[8], a1[8];
      #pragma unroll
      for (int r = 0; r < 8; ++r){ a0[r] = cx0[r]; a1[r] = cx1[r]; }
      for (int k0 = 0; k0 < DZ; k0 += 4){
        f32x4 zr4[8];
        #pragma unroll
        for (int r = 0; r < 8; ++r) zr4[r] = *(const f32x4*)&zsh[r][k0];
        float w0[4], w1[4];
        #pragma unroll
        for (int j = 0; j < 4; ++j){
          w0[j] = W1[(k0 + j) * DH + c0];
          w1[j] = W1[(k0 + j) * DH + c1];
        }
        #pragma unroll
        for (int j = 0; j < 4; ++j){
          #pragma unroll
          for (int r = 0; r < 8; ++r){
            a0[r] = fmaf(zr4[r][j], w0[j], a0[r]);
            a1[r] = fmaf(zr4[r][j], w1[j], a1[r]);
          }
        }
      }
      const float bias0 = b1c0 + ts * wtc0, bias1 = b1c1 + ts * wtc1;
      #pragma unroll
      for (int r = 0; r < 8; ++r){
        hsh[r][c0] = tanh_fast(a0[r] + bias0);
        hsh[r][c1] = tanh_fast(a1[r] + bias1);
      }
      __syncthreads();   // hsh complete

      // ---- GEMM2: k = h@W2 + b2 ----
      float acc2[4] = {0.f, 0.f, 0.f, 0.f};
      for (int k0 = 0; k0 < DH; k0 += 4){
        f32x4 hr4[4];
        #pragma unroll
        for (int i = 0; i < 4; ++i) hr4[i] = *(const f32x4*)&hsh[r0 + i][k0];
        float w[4];
        #pragma unroll
        for (int j = 0; j < 4; ++j) w[j] = W2[(k0 + j) * DZ + c2];
        #pragma unroll
        for (int j = 0; j < 4; ++j){
          #pragma unroll
          for (int i = 0; i < 4; ++i)
            acc2[i] = fmaf(hr4[i][j], w[j], acc2[i]);
        }
      }

      // ---- RK4 update, write next-stage z ----
      const float csw = (s == 0 || s == 3) ? 1.f : 2.f;
      const float dc  = (s < 2) ? 0.5f * hs : hs;
      #pragma unroll
      for (int i = 0; i < 4; ++i){
        float kv = acc2[i] + b2c;
        za[i] += csw * kv;
        float zn;
        if (s < 3){
          zn = zb[i] + dc * kv;
        } else {
          zb[i] += (hs * (1.f / 6.f)) * za[i];
          za[i] = 0.f;
          zn = zb[i];
        }
        zsh[r0 + i][c2] = zn;
      }
      __syncthreads();   // zsh ready for next stage/step
    }
  }

  #pragma unroll
  for (int i = 0; i < 4; ++i)
    out[(wg * RPW + r0 + i) * DZ + c2] = zb[i];
}

extern "C" void kernel_launch(void* const* d_in, const int* in_sizes, int n_in,
                              void* d_out, int out_size, void* d_ws, size_t ws_size,
                              hipStream_t stream){
  const float* z0 = (const float*)d_in[0];
  const float* tt = (const float*)d_in[1];
  const float* x  = (const float*)d_in[2];
  const float* W1 = (const float*)d_in[3];
  const float* Wx = (const float*)d_in[4];
  const float* wt = (const float*)d_in[5];
  const float* b1 = (const float*)d_in[6];
  const float* W2 = (const float*)d_in[7];
  const float* b2 = (const float*)d_in[8];

  node_f32<<<128, NT, 0, stream>>>(z0, tt, x, W1, Wx, wt, b1, W2, b2, (float*)d_out);
}